// Round 10
// baseline (640.453 us; speedup 1.0000x reference)
//
#include <hip/hip_runtime.h>
#include <hip/hip_cooperative_groups.h>
#include <hip/hip_bf16.h>

namespace cg = cooperative_groups;

// WeisfeilerLehman: labels0 = argmax(x, -1); 3x ordered polynomial hash over edges.
// All arithmetic mod 2^32 (uint32 wrap) == reference int64 truncated to int32.
// R10: single cooperative mega-kernel (256 blocks x 512 threads, 8 grid syncs)
//      replacing 12 serialized dispatches (~10us launch overhead each was the
//      pinned ~300us floor). BROWS=512 -> 196 buckets (balanced bucket phase).
//      Fallback to discrete kernels if cooperative launch is rejected.

#define WL_D 128
#define NB 256              // grid size == MSD chunk count
#define BT 512              // threads per block (8 waves)
#define MSDW 8              // waves per block
#define BBITS 9             // bucket = row >> 9 (512 rows/bucket)
#define BROWS 512           // rows per bucket
#define RLSHIFT 23          // packed: (rl << 23) | col   (col < 2^23)
#define NBK 256             // max buckets (N <= 131072)

constexpr unsigned cpow(unsigned b, unsigned e) {
    unsigned p = 1;
    while (e) { if (e & 1u) p *= b; b *= b; e >>= 1u; }
    return p;
}
constexpr unsigned cinv31() {           // Newton: inverse of 31 mod 2^32
    unsigned x = 1;
    for (int i = 0; i < 6; ++i) x *= 2u - 31u * x;
    return x;
}
constexpr unsigned INV31_64 = cpow(cinv31(), 64);   // 31^-64 mod 2^32

__device__ inline unsigned dpow31(unsigned e) {
    unsigned p = 1, b = 31u;
    while (e) { if (e & 1u) p *= b; b *= b; e >>= 1u; }
    return p;
}

// mask of lanes whose low BITS bits of v match mine (inactive lanes use a
// sentinel outside the valid key range so they never match active lanes)
template <int BITS>
__device__ inline unsigned long long match_key(unsigned v) {
    unsigned long long m = ~0ull;
    #pragma unroll
    for (int b = 0; b < BITS; ++b) {
        unsigned long long s = __ballot((v >> b) & 1u);
        m &= ((v >> b) & 1u) ? s : ~s;
    }
    return m;
}

#define SMEMW (MSDW * BROWS + BROWS)    // 4608 words: max over phases (~18.4 KB)

// ---------------- phase device functions (shared by mega + fallback) ----------

__device__ void phase_hist_argmax(unsigned* smem, const float* __restrict__ x,
                                  const int* __restrict__ ei, unsigned* __restrict__ lab0,
                                  unsigned* __restrict__ hist, int N, int E, int chunk,
                                  int nbuckets) {
    int b = blockIdx.x, t = threadIdx.x, lane = t & 63, w = t >> 6;
    for (int i = t; i < nbuckets; i += BT) smem[i] = 0u;
    __syncthreads();
    int base = b * chunk, lim = min(base + chunk, E);
    for (int e = base + t; e < lim; e += BT)
        atomicAdd(&smem[((unsigned)ei[e]) >> BBITS], 1u);   // LDS atomic
    __syncthreads();
    for (int v = t; v < nbuckets; v += BT) hist[(size_t)v * NB + b] = smem[v];
    // argmax: one wave per row, grid-stride
    for (int r = b * MSDW + w; r < N; r += gridDim.x * MSDW) {
        const float* xr = x + (size_t)r * WL_D;
        float v0 = xr[lane], v1 = xr[lane + 64];
        float bv; int bi;
        if (v1 > v0) { bv = v1; bi = lane + 64; } else { bv = v0; bi = lane; }
        #pragma unroll
        for (int off = 32; off > 0; off >>= 1) {
            float ov = __shfl_down(bv, off, 64);
            int   oi = __shfl_down(bi, off, 64);
            if (ov > bv || (ov == bv && oi < bi)) { bv = ov; bi = oi; }
        }
        if (lane == 0) lab0[r] = (unsigned)bi;
    }
}

// tile scan: block b handles flat entries [b*1024, b*1024+1024), 2 per thread
__device__ void phase_scan_tile(unsigned* smem, unsigned* __restrict__ hist,
                                unsigned* __restrict__ bsums, int L) {
    int b = blockIdx.x, t = threadIdx.x;
    int i0 = b * 1024;
    unsigned v0 = (i0 + 2 * t     < L) ? hist[i0 + 2 * t]     : 0u;
    unsigned v1 = (i0 + 2 * t + 1 < L) ? hist[i0 + 2 * t + 1] : 0u;
    unsigned s = v0 + v1;
    smem[t] = s;
    __syncthreads();
    for (int o = 1; o < BT; o <<= 1) {
        unsigned u = (t >= o) ? smem[t - o] : 0u;
        __syncthreads();
        smem[t] += u;
        __syncthreads();
    }
    unsigned excl = smem[t] - s;
    if (i0 + 2 * t     < L) hist[i0 + 2 * t]     = excl;
    if (i0 + 2 * t + 1 < L) hist[i0 + 2 * t + 1] = excl + v0;
    if (t == BT - 1) bsums[b] = smem[BT - 1];
}

__device__ void phase_scan_sums(unsigned* smem, unsigned* __restrict__ bsums, int ntiles) {
    int t = threadIdx.x;
    unsigned v = (t < ntiles) ? bsums[t] : 0u;
    smem[t] = v;
    __syncthreads();
    for (int o = 1; o < BT; o <<= 1) {
        unsigned u = (t >= o) ? smem[t - o] : 0u;
        __syncthreads();
        smem[t] += u;
        __syncthreads();
    }
    if (t < ntiles) bsums[t] = smem[t] - v;
}

// stable MSD scatter: per-wave sub-chunks, per-(wave,bucket) LDS cursors
__device__ void phase_scatter(unsigned* smem, const int* __restrict__ ei,
                              const unsigned* __restrict__ hist, const unsigned* __restrict__ bsums,
                              unsigned* __restrict__ buf, int E, int chunk, int nbuckets) {
    int b = blockIdx.x, t = threadIdx.x, lane = t & 63, w = t >> 6;
    unsigned long long lmask = (1ull << lane) - 1ull;
    unsigned* wbase = smem;                       // [MSDW][NBK]
    __syncthreads();
    for (int i = t; i < MSDW * NBK; i += BT) wbase[i] = 0u;
    __syncthreads();
    int base = b * chunk, lim = min(base + chunk, E);
    int sub  = (chunk + MSDW - 1) / MSDW;
    int wbeg = base + w * sub;
    int wend = min(wbeg + sub, lim);
    int nbat = (wbeg < wend) ? ((wend - wbeg + 63) >> 6) : 0;
    for (int bt2 = 0; bt2 < nbat; ++bt2) {
        int e = wbeg + bt2 * 64 + lane;
        bool act = (e < wend);
        unsigned v = act ? (((unsigned)ei[e]) >> BBITS) : (NBK - 1u);
        unsigned long long m = match_key<8>(v);
        unsigned before = (unsigned)__popcll(m & lmask);
        unsigned total  = (unsigned)__popcll(m);
        if (act && before == 0u) wbase[w * NBK + v] += total;
    }
    __syncthreads();
    for (int v = t; v < nbuckets; v += BT) {
        size_t idx = (size_t)v * NB + b;
        unsigned g = hist[idx] + bsums[idx >> 10];
        #pragma unroll
        for (int w2 = 0; w2 < MSDW; ++w2) {
            unsigned cnt = wbase[w2 * NBK + v];
            wbase[w2 * NBK + v] = g;
            g += cnt;
        }
    }
    __syncthreads();
    for (int bt2 = 0; bt2 < nbat; ++bt2) {
        int e = wbeg + bt2 * 64 + lane;
        bool act = (e < wend);
        unsigned r   = act ? (unsigned)ei[e] : 0u;
        unsigned col = act ? (unsigned)ei[(size_t)E + e] : 0u;
        unsigned v = act ? (r >> BBITS) : (NBK - 1u);
        unsigned long long m = match_key<8>(v);
        unsigned before = (unsigned)__popcll(m & lmask);
        unsigned total  = (unsigned)__popcll(m);
        int leader = __ffsll(m) - 1;
        unsigned base0 = 0;
        if (act && before == 0u) { base0 = wbase[w * NBK + v]; wbase[w * NBK + v] = base0 + total; }
        base0 = __shfl(base0, leader, 64);
        if (act) buf[base0 + before] = ((r & (BROWS - 1u)) << RLSHIFT) | col;
    }
}

// per-bucket stable counting sort by rl; emits rs, deg, ordered col-CSR
__device__ void phase_bucket(unsigned* smem, int bb, const unsigned* __restrict__ buf,
                             const unsigned* __restrict__ hist, const unsigned* __restrict__ bsums,
                             unsigned* __restrict__ csr, unsigned* __restrict__ rs_g,
                             unsigned* __restrict__ deg_g, int N, int E, int nbuckets) {
    int t = threadIdx.x, lane = t & 63, w = t >> 6;
    unsigned long long lmask = (1ull << lane) - 1ull;
    unsigned* h2  = smem;                 // [MSDW][BROWS]
    unsigned* off = smem + MSDW * BROWS;  // [BROWS]
    __syncthreads();
    for (int i = t; i < MSDW * BROWS; i += BT) h2[i] = 0u;
    __syncthreads();
    size_t i0 = (size_t)bb * NB;
    unsigned start = hist[i0] + bsums[i0 >> 10];
    unsigned end;
    if (bb + 1 < nbuckets) { size_t i1 = (size_t)(bb + 1) * NB; end = hist[i1] + bsums[i1 >> 10]; }
    else end = (unsigned)E;
    unsigned len = end - start;
    unsigned sub  = (len + MSDW - 1u) / MSDW;
    unsigned wbeg = w * sub;
    unsigned wend = min(wbeg + sub, len);
    int nbat = (wbeg < wend) ? (int)((wend - wbeg + 63u) >> 6) : 0;
    for (int bt2 = 0; bt2 < nbat; ++bt2) {
        unsigned i = wbeg + (unsigned)(bt2 * 64 + lane);
        bool act = (i < wend);
        unsigned v = act ? (buf[start + i] >> RLSHIFT) : 1023u;   // sentinel >= BROWS
        unsigned long long m = match_key<10>(v);
        unsigned before = (unsigned)__popcll(m & lmask);
        unsigned total  = (unsigned)__popcll(m);
        if (act && before == 0u) h2[w * BROWS + v] += total;
    }
    __syncthreads();
    // deg + exclusive scan over rl (BROWS == BT == 512)
    unsigned hv = 0;
    #pragma unroll
    for (int w2 = 0; w2 < MSDW; ++w2) hv += h2[w2 * BROWS + t];
    off[t] = hv;
    __syncthreads();
    for (int o = 1; o < BROWS; o <<= 1) {
        unsigned s = (t >= o) ? off[t - o] : 0u;
        __syncthreads();
        off[t] += s;
        __syncthreads();
    }
    {
        unsigned excl = off[t] - hv;
        int row = bb * BROWS + t;
        if (row < N) { rs_g[row] = start + excl; deg_g[row] = hv; }
        unsigned g = start + excl;
        #pragma unroll
        for (int w2 = 0; w2 < MSDW; ++w2) {
            unsigned cnt = h2[w2 * BROWS + t];
            h2[w2 * BROWS + t] = g;
            g += cnt;
        }
    }
    __syncthreads();
    for (int bt2 = 0; bt2 < nbat; ++bt2) {
        unsigned i = wbeg + (unsigned)(bt2 * 64 + lane);
        bool act = (i < wend);
        unsigned p = act ? buf[start + i] : 0u;
        unsigned v = act ? (p >> RLSHIFT) : 1023u;
        unsigned long long m = match_key<10>(v);
        unsigned before = (unsigned)__popcll(m & lmask);
        unsigned total  = (unsigned)__popcll(m);
        int leader = __ffsll(m) - 1;
        unsigned base0 = 0;
        if (act && before == 0u) { base0 = h2[w * BROWS + v]; h2[w * BROWS + v] = base0 + total; }
        base0 = __shfl(base0, leader, 64);
        if (act) csr[base0 + before] = p & ((1u << RLSHIFT) - 1u);
    }
}

// one wave per row: new[r] = sum_j lab[col_j] * 31^(d-1-j)  (mod 2^32)
__device__ void phase_prop(const unsigned* __restrict__ csr, const unsigned* __restrict__ rs,
                           const unsigned* __restrict__ deg, const unsigned* __restrict__ lin,
                           unsigned* __restrict__ lout, int N) {
    int t = threadIdx.x, lane = t & 63, w = t >> 6;
    for (int r = blockIdx.x * MSDW + w; r < N; r += gridDim.x * MSDW) {
        unsigned start = rs[r], d = deg[r];
        unsigned acc = 0;
        if ((unsigned)lane < d) {
            unsigned p = dpow31(d - 1u - (unsigned)lane);
            for (unsigned j = (unsigned)lane; j < d; j += 64u) {
                acc += lin[csr[start + j]] * p;
                p *= INV31_64;
            }
        }
        #pragma unroll
        for (int o = 32; o > 0; o >>= 1) acc += __shfl_xor(acc, o, 64);
        if (lane == 0) lout[r] = acc;
    }
}

__device__ void phase_out(const unsigned* __restrict__ l0, const unsigned* __restrict__ l1,
                          const unsigned* __restrict__ l2, const unsigned* __restrict__ l3,
                          int* __restrict__ out, int N) {
    for (int i = blockIdx.x * BT + threadIdx.x; i < N; i += gridDim.x * BT) {
        int a0 = (int)l0[i], a1 = (int)l1[i], a2 = (int)l2[i], a3 = (int)l3[i];
        out[i]         = a3;
        out[N + i]     = a0;
        out[2 * N + i] = a1;
        out[3 * N + i] = a2;
        out[4 * N + i] = a3;
    }
}

// ---------------- cooperative mega-kernel ----------------

__global__ void __launch_bounds__(BT)
wl_mega(const float* __restrict__ x, const int* __restrict__ ei, int* __restrict__ out,
        unsigned* lab0, unsigned* lab1, unsigned* lab2, unsigned* lab3,
        unsigned* rs, unsigned* deg, unsigned* bsums, unsigned* hist,
        unsigned* buf, unsigned* csr,
        int N, int E, int chunk, int nbuckets, int L, int ntiles) {
    cg::grid_group grid = cg::this_grid();
    __shared__ unsigned smem[SMEMW];
    int b = blockIdx.x;

    phase_hist_argmax(smem, x, ei, lab0, hist, N, E, chunk, nbuckets);
    grid.sync();
    if (b < ntiles) phase_scan_tile(smem, hist, bsums, L);
    grid.sync();
    if (b == 0) phase_scan_sums(smem, bsums, ntiles);
    grid.sync();
    phase_scatter(smem, ei, hist, bsums, buf, E, chunk, nbuckets);
    grid.sync();
    for (int bb = b; bb < nbuckets; bb += NB)
        phase_bucket(smem, bb, buf, hist, bsums, csr, rs, deg, N, E, nbuckets);
    grid.sync();
    phase_prop(csr, rs, deg, lab0, lab1, N);
    grid.sync();
    phase_prop(csr, rs, deg, lab1, lab2, N);
    grid.sync();
    phase_prop(csr, rs, deg, lab2, lab3, N);
    grid.sync();
    phase_out(lab0, lab1, lab2, lab3, out, N);
}

// ---------------- discrete fallback kernels (same phases) ----------------

__global__ void __launch_bounds__(BT)
k_hist_argmax(const float* x, const int* ei, unsigned* lab0, unsigned* hist,
              int N, int E, int chunk, int nbuckets) {
    __shared__ unsigned smem[SMEMW];
    phase_hist_argmax(smem, x, ei, lab0, hist, N, E, chunk, nbuckets);
}
__global__ void __launch_bounds__(BT)
k_scan_tile(unsigned* hist, unsigned* bsums, int L) {
    __shared__ unsigned smem[SMEMW];
    phase_scan_tile(smem, hist, bsums, L);
}
__global__ void __launch_bounds__(BT)
k_scan_sums(unsigned* bsums, int ntiles) {
    __shared__ unsigned smem[SMEMW];
    phase_scan_sums(smem, bsums, ntiles);
}
__global__ void __launch_bounds__(BT)
k_scatter(const int* ei, const unsigned* hist, const unsigned* bsums, unsigned* buf,
          int E, int chunk, int nbuckets) {
    __shared__ unsigned smem[SMEMW];
    phase_scatter(smem, ei, hist, bsums, buf, E, chunk, nbuckets);
}
__global__ void __launch_bounds__(BT)
k_bucket(const unsigned* buf, const unsigned* hist, const unsigned* bsums, unsigned* csr,
         unsigned* rs, unsigned* deg, int N, int E, int nbuckets) {
    __shared__ unsigned smem[SMEMW];
    phase_bucket(smem, blockIdx.x, buf, hist, bsums, csr, rs, deg, N, E, nbuckets);
}
__global__ void __launch_bounds__(BT)
k_prop(const unsigned* csr, const unsigned* rs, const unsigned* deg,
       const unsigned* lin, unsigned* lout, int N) {
    phase_prop(csr, rs, deg, lin, lout, N);
}
__global__ void __launch_bounds__(BT)
k_out(const unsigned* l0, const unsigned* l1, const unsigned* l2, const unsigned* l3,
      int* out, int N) {
    phase_out(l0, l1, l2, l3, out, N);
}

extern "C" void kernel_launch(void* const* d_in, const int* in_sizes, int n_in,
                              void* d_out, int out_size, void* d_ws, size_t ws_size,
                              hipStream_t stream) {
    const float* x  = (const float*)d_in[0];
    const int*   ei = (const int*)d_in[1];
    int* out = (int*)d_out;

    int N = in_sizes[0] / WL_D;
    int E = in_sizes[1] / 2;
    int chunk    = (E + NB - 1) / NB;          // 12500
    int nbuckets = (N + BROWS - 1) / BROWS;    // 196
    int L        = nbuckets * NB;              // 50,176
    int ntiles   = (L + 1023) / 1024;          // 49

    // workspace layout (uint32 units) — everything written before read, no memset
    unsigned* ws   = (unsigned*)d_ws;
    unsigned* lab0 = ws;               // N
    unsigned* lab1 = lab0 + N;         // N
    unsigned* lab2 = lab1 + N;         // N
    unsigned* lab3 = lab2 + N;         // N
    unsigned* rs   = lab3 + N;         // N
    unsigned* deg  = rs + N;           // N
    unsigned* bs   = deg + N;          // 1024
    unsigned* hist = bs + 1024;        // L
    unsigned* buf  = hist + L;         // E
    unsigned* csr  = buf + E;          // E

    void* args[] = { (void*)&x, (void*)&ei, (void*)&out,
                     (void*)&lab0, (void*)&lab1, (void*)&lab2, (void*)&lab3,
                     (void*)&rs, (void*)&deg, (void*)&bs, (void*)&hist,
                     (void*)&buf, (void*)&csr,
                     (void*)&N, (void*)&E, (void*)&chunk, (void*)&nbuckets,
                     (void*)&L, (void*)&ntiles };
    hipError_t err = hipLaunchCooperativeKernel((void*)wl_mega, dim3(NB), dim3(BT),
                                                args, 0, stream);
    if (err != hipSuccess) {
        // deterministic fallback: identical phases as discrete kernels
        k_hist_argmax<<<NB, BT, 0, stream>>>(x, ei, lab0, hist, N, E, chunk, nbuckets);
        k_scan_tile<<<ntiles, BT, 0, stream>>>(hist, bs, L);
        k_scan_sums<<<1, BT, 0, stream>>>(bs, ntiles);
        k_scatter<<<NB, BT, 0, stream>>>(ei, hist, bs, buf, E, chunk, nbuckets);
        k_bucket<<<nbuckets, BT, 0, stream>>>(buf, hist, bs, csr, rs, deg, N, E, nbuckets);
        k_prop<<<NB, BT, 0, stream>>>(csr, rs, deg, lab0, lab1, N);
        k_prop<<<NB, BT, 0, stream>>>(csr, rs, deg, lab1, lab2, N);
        k_prop<<<NB, BT, 0, stream>>>(csr, rs, deg, lab2, lab3, N);
        k_out<<<NB, BT, 0, stream>>>(lab0, lab1, lab2, lab3, out, N);
    }
}

// Round 11
// 300.932 us; speedup vs baseline: 2.1282x; 2.1282x over previous
//
#include <hip/hip_runtime.h>
#include <hip/hip_bf16.h>

// WeisfeilerLehman: labels0 = argmax(x, -1); 3x ordered polynomial hash over edges.
// All arithmetic mod 2^32 (uint32 wrap) == reference int64 truncated to int32.
// R11: discrete launches (R10 mega regressed 2x: 1 block/CU killed latency hiding).
//      New bucket-centric prop (binary-search row lookup + LDS accumulate, full
//      lane utilization); bucket_sort stages slice in LDS; hist+argmax+zero fused.
//      9 launches. BROWS=512 -> 196 buckets.

#define WL_D 128
#define NB 256              // MSD chunks == scatter/hist grid
#define BT 512              // threads per block (8 waves)
#define MSDW 8
#define BBITS 9             // bucket = row >> 9
#define BROWS 512           // rows per bucket
#define NBK 256             // max buckets (N <= 131072)
#define RLSHIFT 23          // buf pack: (rl << 23) | col   (col < 2^23)
#define COLMASK ((1u << RLSHIFT) - 1u)
#define CMAX 20480          // LDS-staged slice cap (80 KB)
#define SPLIT 2             // prop blocks per bucket

__device__ inline unsigned dpow31(unsigned e) {
    unsigned p = 1, b = 31u;
    while (e) { if (e & 1u) p *= b; b *= b; e >>= 1u; }
    return p;
}

// mask of lanes whose low BITS bits of v match mine (inactive lanes use a
// sentinel outside the valid key range so they never match active lanes)
template <int BITS>
__device__ inline unsigned long long match_key(unsigned v) {
    unsigned long long m = ~0ull;
    #pragma unroll
    for (int b = 0; b < BITS; ++b) {
        unsigned long long s = __ballot((v >> b) & 1u);
        m &= ((v >> b) & 1u) ? s : ~s;
    }
    return m;
}

// ---- fused: chunk bucket-histogram + argmax + zero lab1..3 ----
__global__ void __launch_bounds__(BT)
k_hist_argmax(const float* __restrict__ x, const int* __restrict__ ei,
              unsigned* __restrict__ lab0, unsigned* __restrict__ hist,
              unsigned* __restrict__ zero3, int N, int E, int chunk, int nbuckets) {
    __shared__ unsigned h[NBK];
    int b = blockIdx.x, t = threadIdx.x, lane = t & 63, w = t >> 6;
    for (int i = t; i < nbuckets; i += BT) h[i] = 0u;
    __syncthreads();
    int base = b * chunk, lim = min(base + chunk, E);
    for (int e = base + t; e < lim; e += BT)
        atomicAdd(&h[((unsigned)ei[e]) >> BBITS], 1u);
    __syncthreads();
    for (int v = t; v < nbuckets; v += BT) hist[(size_t)v * NB + b] = h[v];
    // zero lab1..lab3 (contiguous 3N words)
    for (int i = b * BT + t; i < 3 * N; i += NB * BT) zero3[i] = 0u;
    // argmax: one wave per row, float2 loads
    for (int r = b * MSDW + w; r < N; r += NB * MSDW) {
        const float2* xr = (const float2*)(x + (size_t)r * WL_D);
        float2 v = xr[lane];
        float bv; int bi;
        if (v.y > v.x) { bv = v.y; bi = 2 * lane + 1; } else { bv = v.x; bi = 2 * lane; }
        #pragma unroll
        for (int off = 32; off > 0; off >>= 1) {
            float ov = __shfl_down(bv, off, 64);
            int   oi = __shfl_down(bi, off, 64);
            if (ov > bv || (ov == bv && oi < bi)) { bv = ov; bi = oi; }
        }
        if (lane == 0) lab0[r] = (unsigned)bi;
    }
}

// ---- scan: tile (1024 elems / block, 2 per thread) + sums ----
__global__ void __launch_bounds__(BT)
k_scan_tile(unsigned* __restrict__ hist, unsigned* __restrict__ bsums, int L) {
    __shared__ unsigned smem[BT];
    int b = blockIdx.x, t = threadIdx.x;
    int i0 = b * 1024;
    unsigned v0 = (i0 + 2 * t     < L) ? hist[i0 + 2 * t]     : 0u;
    unsigned v1 = (i0 + 2 * t + 1 < L) ? hist[i0 + 2 * t + 1] : 0u;
    unsigned s = v0 + v1;
    smem[t] = s;
    __syncthreads();
    for (int o = 1; o < BT; o <<= 1) {
        unsigned u = (t >= o) ? smem[t - o] : 0u;
        __syncthreads();
        smem[t] += u;
        __syncthreads();
    }
    unsigned excl = smem[t] - s;
    if (i0 + 2 * t     < L) hist[i0 + 2 * t]     = excl;
    if (i0 + 2 * t + 1 < L) hist[i0 + 2 * t + 1] = excl + v0;
    if (t == BT - 1) bsums[b] = smem[BT - 1];
}

__global__ void __launch_bounds__(BT)
k_scan_sums(unsigned* __restrict__ bsums, int ntiles) {
    __shared__ unsigned smem[BT];
    int t = threadIdx.x;
    unsigned v = (t < ntiles) ? bsums[t] : 0u;
    smem[t] = v;
    __syncthreads();
    for (int o = 1; o < BT; o <<= 1) {
        unsigned u = (t >= o) ? smem[t - o] : 0u;
        __syncthreads();
        smem[t] += u;
        __syncthreads();
    }
    if (t < ntiles) bsums[t] = smem[t] - v;
}

// ---- stable MSD scatter: per-wave sub-chunks, per-(wave,bucket) LDS cursors ----
__global__ void __launch_bounds__(BT)
k_scatter(const int* __restrict__ ei, const unsigned* __restrict__ hist,
          const unsigned* __restrict__ bsums, unsigned* __restrict__ buf,
          int E, int chunk, int nbuckets) {
    __shared__ unsigned wbase[MSDW * NBK];   // 8 KB
    int b = blockIdx.x, t = threadIdx.x, lane = t & 63, w = t >> 6;
    unsigned long long lmask = (1ull << lane) - 1ull;
    for (int i = t; i < MSDW * NBK; i += BT) wbase[i] = 0u;
    __syncthreads();
    int base = b * chunk, lim = min(base + chunk, E);
    int sub  = (chunk + MSDW - 1) / MSDW;
    int wbeg = base + w * sub;
    int wend = min(wbeg + sub, lim);
    int nbat = (wbeg < wend) ? ((wend - wbeg + 63) >> 6) : 0;
    for (int bt2 = 0; bt2 < nbat; ++bt2) {
        int e = wbeg + bt2 * 64 + lane;
        bool act = (e < wend);
        unsigned v = act ? (((unsigned)ei[e]) >> BBITS) : (NBK - 1u);
        unsigned long long m = match_key<8>(v);
        unsigned before = (unsigned)__popcll(m & lmask);
        unsigned total  = (unsigned)__popcll(m);
        if (act && before == 0u) wbase[w * NBK + v] += total;
    }
    __syncthreads();
    for (int v = t; v < nbuckets; v += BT) {
        size_t idx = (size_t)v * NB + b;
        unsigned g = hist[idx] + bsums[idx >> 10];
        #pragma unroll
        for (int w2 = 0; w2 < MSDW; ++w2) {
            unsigned cnt = wbase[w2 * NBK + v];
            wbase[w2 * NBK + v] = g;
            g += cnt;
        }
    }
    __syncthreads();
    for (int bt2 = 0; bt2 < nbat; ++bt2) {
        int e = wbeg + bt2 * 64 + lane;
        bool act = (e < wend);
        unsigned r   = act ? (unsigned)ei[e] : 0u;
        unsigned col = act ? (unsigned)ei[(size_t)E + e] : 0u;
        unsigned v = act ? (r >> BBITS) : (NBK - 1u);
        unsigned long long m = match_key<8>(v);
        unsigned before = (unsigned)__popcll(m & lmask);
        unsigned total  = (unsigned)__popcll(m);
        int leader = __ffsll(m) - 1;
        unsigned base0 = 0;
        if (act && before == 0u) { base0 = wbase[w * NBK + v]; wbase[w * NBK + v] = base0 + total; }
        base0 = __shfl(base0, leader, 64);
        if (act) buf[base0 + before] = ((r & (BROWS - 1u)) << RLSHIFT) | col;
    }
}

// ---- per-bucket stable counting sort by rl (slice staged in LDS); emits rs + csr ----
__global__ void __launch_bounds__(BT)
k_bucket(const unsigned* __restrict__ buf, const unsigned* __restrict__ hist,
         const unsigned* __restrict__ bsums, unsigned* __restrict__ csr,
         unsigned* __restrict__ rs_g, int N, int E, int nbuckets) {
    __shared__ unsigned data[CMAX];           // 80 KB
    __shared__ unsigned h2[MSDW * BROWS];     // 16 KB
    __shared__ unsigned offs[BROWS];          // 2 KB
    int bb = blockIdx.x, t = threadIdx.x, lane = t & 63, w = t >> 6;
    unsigned long long lmask = (1ull << lane) - 1ull;
    size_t i0 = (size_t)bb * NB;
    unsigned start = hist[i0] + bsums[i0 >> 10];
    unsigned end;
    if (bb + 1 < nbuckets) { size_t i1 = (size_t)(bb + 1) * NB; end = hist[i1] + bsums[i1 >> 10]; }
    else end = (unsigned)E;
    unsigned len = end - start;
    bool lds_ok = (len <= CMAX);
    if (lds_ok) for (unsigned i = t; i < len; i += BT) data[i] = buf[start + i];
    for (int i = t; i < MSDW * BROWS; i += BT) h2[i] = 0u;
    __syncthreads();
    unsigned sub  = (len + MSDW - 1u) / MSDW;
    unsigned wbeg = w * sub;
    unsigned wend = min(wbeg + sub, len);
    int nbat = (wbeg < wend) ? (int)((wend - wbeg + 63u) >> 6) : 0;
    // pass A: per-wave rl counts
    for (int bt2 = 0; bt2 < nbat; ++bt2) {
        unsigned i = wbeg + (unsigned)(bt2 * 64 + lane);
        bool act = (i < wend);
        unsigned v = act ? ((lds_ok ? data[i] : buf[start + i]) >> RLSHIFT) : 1023u;
        unsigned long long m = match_key<10>(v);
        unsigned before = (unsigned)__popcll(m & lmask);
        unsigned total  = (unsigned)__popcll(m);
        if (act && before == 0u) h2[w * BROWS + v] += total;
    }
    __syncthreads();
    // exclusive scan over rl; emit rs; seed per-wave cursors
    unsigned hv = 0;
    #pragma unroll
    for (int w2 = 0; w2 < MSDW; ++w2) hv += h2[w2 * BROWS + t];
    offs[t] = hv;
    __syncthreads();
    for (int o = 1; o < BROWS; o <<= 1) {
        unsigned s = (t >= o) ? offs[t - o] : 0u;
        __syncthreads();
        offs[t] += s;
        __syncthreads();
    }
    {
        unsigned excl = offs[t] - hv;
        int row = bb * BROWS + t;
        if (row < N) rs_g[row] = start + excl;
        unsigned g = start + excl;
        #pragma unroll
        for (int w2 = 0; w2 < MSDW; ++w2) {
            unsigned cnt = h2[w2 * BROWS + t];
            h2[w2 * BROWS + t] = g;
            g += cnt;
        }
    }
    __syncthreads();
    // pass B: stable scatter cols into csr
    for (int bt2 = 0; bt2 < nbat; ++bt2) {
        unsigned i = wbeg + (unsigned)(bt2 * 64 + lane);
        bool act = (i < wend);
        unsigned p = act ? (lds_ok ? data[i] : buf[start + i]) : 0u;
        unsigned v = act ? (p >> RLSHIFT) : 1023u;
        unsigned long long m = match_key<10>(v);
        unsigned before = (unsigned)__popcll(m & lmask);
        unsigned total  = (unsigned)__popcll(m);
        int leader = __ffsll(m) - 1;
        unsigned base0 = 0;
        if (act && before == 0u) { base0 = h2[w * BROWS + v]; h2[w * BROWS + v] = base0 + total; }
        base0 = __shfl(base0, leader, 64);
        if (act) csr[base0 + before] = p & COLMASK;
    }
}

// ---- prop: block per (bucket, half); binary-search row, LDS accumulate ----
__global__ void __launch_bounds__(BT)
k_prop(const unsigned* __restrict__ csr, const unsigned* __restrict__ rs,
       const unsigned* __restrict__ hist, const unsigned* __restrict__ bsums,
       const unsigned* __restrict__ lin, unsigned* __restrict__ lout,
       int N, int E, int nbuckets) {
    __shared__ unsigned acc[BROWS];
    __shared__ unsigned offs[BROWS + 1];
    __shared__ unsigned pwt[BROWS];
    int bb = blockIdx.x / SPLIT, pp = blockIdx.x % SPLIT;
    int t = threadIdx.x;
    size_t i0 = (size_t)bb * NB;
    unsigned start = hist[i0] + bsums[i0 >> 10];
    unsigned end;
    if (bb + 1 < nbuckets) { size_t i1 = (size_t)(bb + 1) * NB; end = hist[i1] + bsums[i1 >> 10]; }
    else end = (unsigned)E;
    unsigned len = end - start;
    acc[t] = 0u;
    pwt[t] = dpow31((unsigned)t);
    int row = bb * BROWS + t;
    offs[t] = (row < N) ? (rs[row] - start) : len;
    if (t == 0) offs[BROWS] = len;
    __syncthreads();
    unsigned seglen = (len + SPLIT - 1u) / SPLIT;
    unsigned pbeg = pp * seglen;
    unsigned pend = min(pbeg + seglen, len);
    for (unsigned i = pbeg + t; i < pend; i += BT) {
        unsigned col = csr[start + i];
        int lo = 0;
        #pragma unroll
        for (int st = 256; st; st >>= 1) {
            int mid = lo + st;
            if (offs[mid] <= i) lo = mid;
        }
        unsigned ex = offs[lo + 1] - 1u - i;
        unsigned val = lin[col] * ((ex < BROWS) ? pwt[ex] : dpow31(ex));
        atomicAdd(&acc[lo], val);
    }
    __syncthreads();
    if (row < N) atomicAdd(&lout[row], acc[t]);
}

__global__ void __launch_bounds__(BT)
k_out(const unsigned* __restrict__ l0, const unsigned* __restrict__ l1,
      const unsigned* __restrict__ l2, const unsigned* __restrict__ l3,
      int* __restrict__ out, int N) {
    for (int i = blockIdx.x * BT + threadIdx.x; i < N; i += NB * BT) {
        int a0 = (int)l0[i], a1 = (int)l1[i], a2 = (int)l2[i], a3 = (int)l3[i];
        out[i]         = a3;
        out[N + i]     = a0;
        out[2 * N + i] = a1;
        out[3 * N + i] = a2;
        out[4 * N + i] = a3;
    }
}

extern "C" void kernel_launch(void* const* d_in, const int* in_sizes, int n_in,
                              void* d_out, int out_size, void* d_ws, size_t ws_size,
                              hipStream_t stream) {
    const float* x  = (const float*)d_in[0];
    const int*   ei = (const int*)d_in[1];
    int* out = (int*)d_out;

    int N = in_sizes[0] / WL_D;
    int E = in_sizes[1] / 2;
    int chunk    = (E + NB - 1) / NB;          // 12500
    int nbuckets = (N + BROWS - 1) / BROWS;    // 196
    int L        = nbuckets * NB;              // 50,176
    int ntiles   = (L + 1023) / 1024;          // 49

    // workspace layout (uint32 units) — everything written before read
    unsigned* ws   = (unsigned*)d_ws;
    unsigned* lab0 = ws;               // N
    unsigned* lab1 = lab0 + N;         // N  (zeroed in k_hist_argmax)
    unsigned* lab2 = lab1 + N;         // N  (zeroed)
    unsigned* lab3 = lab2 + N;         // N  (zeroed)
    unsigned* rs   = lab3 + N;         // N
    unsigned* bs   = rs + N;           // 1024
    unsigned* hist = bs + 1024;        // L
    unsigned* buf  = hist + L;         // E
    unsigned* csr  = buf + E;          // E

    k_hist_argmax<<<NB, BT, 0, stream>>>(x, ei, lab0, hist, lab1, N, E, chunk, nbuckets);
    k_scan_tile<<<ntiles, BT, 0, stream>>>(hist, bs, L);
    k_scan_sums<<<1, BT, 0, stream>>>(bs, ntiles);
    k_scatter<<<NB, BT, 0, stream>>>(ei, hist, bs, buf, E, chunk, nbuckets);
    k_bucket<<<nbuckets, BT, 0, stream>>>(buf, hist, bs, csr, rs, N, E, nbuckets);
    k_prop<<<nbuckets * SPLIT, BT, 0, stream>>>(csr, rs, hist, bs, lab0, lab1, N, E, nbuckets);
    k_prop<<<nbuckets * SPLIT, BT, 0, stream>>>(csr, rs, hist, bs, lab1, lab2, N, E, nbuckets);
    k_prop<<<nbuckets * SPLIT, BT, 0, stream>>>(csr, rs, hist, bs, lab2, lab3, N, E, nbuckets);
    k_out<<<NB, BT, 0, stream>>>(lab0, lab1, lab2, lab3, out, N);
}

// Round 12
// 270.264 us; speedup vs baseline: 2.3697x; 1.1135x over previous
//
#include <hip/hip_runtime.h>
#include <hip/hip_bf16.h>

// WeisfeilerLehman: labels0 = argmax(x, -1); 3x ordered polynomial hash over edges.
// All arithmetic mod 2^32 (uint32 wrap) == reference int64 truncated to int32.
// R12: occupancy fixes. Fused hist/argmax/zero kernel now 2048 blocks (argmax was
//      8 waves/CU -> latency-bound at 60us); MSD chunks 256->512 so scatter runs
//      at 2 blocks/CU. Everything else identical to R11.

#define WL_D 128
#define NCH 512             // MSD chunk count (scatter grid)
#define GRID_F 2048         // fused hist/argmax/zero grid
#define BT 512              // threads per block (8 waves)
#define MSDW 8
#define BBITS 9             // bucket = row >> 9
#define BROWS 512           // rows per bucket
#define NBK 256             // max buckets (N <= 131072)
#define RLSHIFT 23          // buf pack: (rl << 23) | col   (col < 2^23)
#define COLMASK ((1u << RLSHIFT) - 1u)
#define CMAX 20480          // LDS-staged slice cap (80 KB)
#define SPLIT 2             // prop blocks per bucket

__device__ inline unsigned dpow31(unsigned e) {
    unsigned p = 1, b = 31u;
    while (e) { if (e & 1u) p *= b; b *= b; e >>= 1u; }
    return p;
}

// mask of lanes whose low BITS bits of v match mine (inactive lanes use a
// sentinel outside the valid key range so they never match active lanes)
template <int BITS>
__device__ inline unsigned long long match_key(unsigned v) {
    unsigned long long m = ~0ull;
    #pragma unroll
    for (int b = 0; b < BITS; ++b) {
        unsigned long long s = __ballot((v >> b) & 1u);
        m &= ((v >> b) & 1u) ? s : ~s;
    }
    return m;
}

// ---- fused: chunk bucket-histogram (blocks < NCH) + argmax + zero lab1..3 ----
__global__ void __launch_bounds__(BT)
k_hist_argmax(const float* __restrict__ x, const int* __restrict__ ei,
              unsigned* __restrict__ lab0, unsigned* __restrict__ hist,
              unsigned* __restrict__ zero3, int N, int E, int chunk, int nbuckets) {
    __shared__ unsigned h[NBK];
    int b = blockIdx.x, t = threadIdx.x, lane = t & 63, w = t >> 6;
    if (b < NCH) {                      // uniform per-block condition: syncs are safe
        for (int i = t; i < nbuckets; i += BT) h[i] = 0u;
        __syncthreads();
        int base = b * chunk, lim = min(base + chunk, E);
        for (int e = base + t; e < lim; e += BT)
            atomicAdd(&h[((unsigned)ei[e]) >> BBITS], 1u);
        __syncthreads();
        for (int v = t; v < nbuckets; v += BT) hist[(size_t)v * NCH + b] = h[v];
    }
    // zero lab1..lab3 (contiguous 3N words)
    for (int i = b * BT + t; i < 3 * N; i += GRID_F * BT) zero3[i] = 0u;
    // argmax: one wave per row, float2 loads, grid-stride
    for (int r = b * MSDW + w; r < N; r += GRID_F * MSDW) {
        const float2* xr = (const float2*)(x + (size_t)r * WL_D);
        float2 v = xr[lane];
        float bv; int bi;
        if (v.y > v.x) { bv = v.y; bi = 2 * lane + 1; } else { bv = v.x; bi = 2 * lane; }
        #pragma unroll
        for (int off = 32; off > 0; off >>= 1) {
            float ov = __shfl_down(bv, off, 64);
            int   oi = __shfl_down(bi, off, 64);
            if (ov > bv || (ov == bv && oi < bi)) { bv = ov; bi = oi; }
        }
        if (lane == 0) lab0[r] = (unsigned)bi;
    }
}

// ---- scan: tile (1024 elems / block, 2 per thread) + sums ----
__global__ void __launch_bounds__(BT)
k_scan_tile(unsigned* __restrict__ hist, unsigned* __restrict__ bsums, int L) {
    __shared__ unsigned smem[BT];
    int b = blockIdx.x, t = threadIdx.x;
    int i0 = b * 1024;
    unsigned v0 = (i0 + 2 * t     < L) ? hist[i0 + 2 * t]     : 0u;
    unsigned v1 = (i0 + 2 * t + 1 < L) ? hist[i0 + 2 * t + 1] : 0u;
    unsigned s = v0 + v1;
    smem[t] = s;
    __syncthreads();
    for (int o = 1; o < BT; o <<= 1) {
        unsigned u = (t >= o) ? smem[t - o] : 0u;
        __syncthreads();
        smem[t] += u;
        __syncthreads();
    }
    unsigned excl = smem[t] - s;
    if (i0 + 2 * t     < L) hist[i0 + 2 * t]     = excl;
    if (i0 + 2 * t + 1 < L) hist[i0 + 2 * t + 1] = excl + v0;
    if (t == BT - 1) bsums[b] = smem[BT - 1];
}

__global__ void __launch_bounds__(BT)
k_scan_sums(unsigned* __restrict__ bsums, int ntiles) {
    __shared__ unsigned smem[BT];
    int t = threadIdx.x;
    unsigned v = (t < ntiles) ? bsums[t] : 0u;
    smem[t] = v;
    __syncthreads();
    for (int o = 1; o < BT; o <<= 1) {
        unsigned u = (t >= o) ? smem[t - o] : 0u;
        __syncthreads();
        smem[t] += u;
        __syncthreads();
    }
    if (t < ntiles) bsums[t] = smem[t] - v;
}

// ---- stable MSD scatter: per-wave sub-chunks, per-(wave,bucket) LDS cursors ----
__global__ void __launch_bounds__(BT)
k_scatter(const int* __restrict__ ei, const unsigned* __restrict__ hist,
          const unsigned* __restrict__ bsums, unsigned* __restrict__ buf,
          int E, int chunk, int nbuckets) {
    __shared__ unsigned wbase[MSDW * NBK];   // 8 KB
    int b = blockIdx.x, t = threadIdx.x, lane = t & 63, w = t >> 6;
    unsigned long long lmask = (1ull << lane) - 1ull;
    for (int i = t; i < MSDW * NBK; i += BT) wbase[i] = 0u;
    __syncthreads();
    int base = b * chunk, lim = min(base + chunk, E);
    int sub  = (chunk + MSDW - 1) / MSDW;
    int wbeg = base + w * sub;
    int wend = min(wbeg + sub, lim);
    int nbat = (wbeg < wend) ? ((wend - wbeg + 63) >> 6) : 0;
    for (int bt2 = 0; bt2 < nbat; ++bt2) {
        int e = wbeg + bt2 * 64 + lane;
        bool act = (e < wend);
        unsigned v = act ? (((unsigned)ei[e]) >> BBITS) : (NBK - 1u);
        unsigned long long m = match_key<8>(v);
        unsigned before = (unsigned)__popcll(m & lmask);
        unsigned total  = (unsigned)__popcll(m);
        if (act && before == 0u) wbase[w * NBK + v] += total;
    }
    __syncthreads();
    for (int v = t; v < nbuckets; v += BT) {
        size_t idx = (size_t)v * NCH + b;
        unsigned g = hist[idx] + bsums[idx >> 10];
        #pragma unroll
        for (int w2 = 0; w2 < MSDW; ++w2) {
            unsigned cnt = wbase[w2 * NBK + v];
            wbase[w2 * NBK + v] = g;
            g += cnt;
        }
    }
    __syncthreads();
    for (int bt2 = 0; bt2 < nbat; ++bt2) {
        int e = wbeg + bt2 * 64 + lane;
        bool act = (e < wend);
        unsigned r   = act ? (unsigned)ei[e] : 0u;
        unsigned col = act ? (unsigned)ei[(size_t)E + e] : 0u;
        unsigned v = act ? (r >> BBITS) : (NBK - 1u);
        unsigned long long m = match_key<8>(v);
        unsigned before = (unsigned)__popcll(m & lmask);
        unsigned total  = (unsigned)__popcll(m);
        int leader = __ffsll(m) - 1;
        unsigned base0 = 0;
        if (act && before == 0u) { base0 = wbase[w * NBK + v]; wbase[w * NBK + v] = base0 + total; }
        base0 = __shfl(base0, leader, 64);
        if (act) buf[base0 + before] = ((r & (BROWS - 1u)) << RLSHIFT) | col;
    }
}

// ---- per-bucket stable counting sort by rl (slice staged in LDS); emits rs + csr ----
__global__ void __launch_bounds__(BT)
k_bucket(const unsigned* __restrict__ buf, const unsigned* __restrict__ hist,
         const unsigned* __restrict__ bsums, unsigned* __restrict__ csr,
         unsigned* __restrict__ rs_g, int N, int E, int nbuckets) {
    __shared__ unsigned data[CMAX];           // 80 KB
    __shared__ unsigned h2[MSDW * BROWS];     // 16 KB
    __shared__ unsigned offs[BROWS];          // 2 KB
    int bb = blockIdx.x, t = threadIdx.x, lane = t & 63, w = t >> 6;
    unsigned long long lmask = (1ull << lane) - 1ull;
    size_t i0 = (size_t)bb * NCH;
    unsigned start = hist[i0] + bsums[i0 >> 10];
    unsigned end;
    if (bb + 1 < nbuckets) { size_t i1 = (size_t)(bb + 1) * NCH; end = hist[i1] + bsums[i1 >> 10]; }
    else end = (unsigned)E;
    unsigned len = end - start;
    bool lds_ok = (len <= CMAX);
    if (lds_ok) for (unsigned i = t; i < len; i += BT) data[i] = buf[start + i];
    for (int i = t; i < MSDW * BROWS; i += BT) h2[i] = 0u;
    __syncthreads();
    unsigned sub  = (len + MSDW - 1u) / MSDW;
    unsigned wbeg = w * sub;
    unsigned wend = min(wbeg + sub, len);
    int nbat = (wbeg < wend) ? (int)((wend - wbeg + 63u) >> 6) : 0;
    // pass A: per-wave rl counts
    for (int bt2 = 0; bt2 < nbat; ++bt2) {
        unsigned i = wbeg + (unsigned)(bt2 * 64 + lane);
        bool act = (i < wend);
        unsigned v = act ? ((lds_ok ? data[i] : buf[start + i]) >> RLSHIFT) : 1023u;
        unsigned long long m = match_key<10>(v);
        unsigned before = (unsigned)__popcll(m & lmask);
        unsigned total  = (unsigned)__popcll(m);
        if (act && before == 0u) h2[w * BROWS + v] += total;
    }
    __syncthreads();
    // exclusive scan over rl; emit rs; seed per-wave cursors
    unsigned hv = 0;
    #pragma unroll
    for (int w2 = 0; w2 < MSDW; ++w2) hv += h2[w2 * BROWS + t];
    offs[t] = hv;
    __syncthreads();
    for (int o = 1; o < BROWS; o <<= 1) {
        unsigned s = (t >= o) ? offs[t - o] : 0u;
        __syncthreads();
        offs[t] += s;
        __syncthreads();
    }
    {
        unsigned excl = offs[t] - hv;
        int row = bb * BROWS + t;
        if (row < N) rs_g[row] = start + excl;
        unsigned g = start + excl;
        #pragma unroll
        for (int w2 = 0; w2 < MSDW; ++w2) {
            unsigned cnt = h2[w2 * BROWS + t];
            h2[w2 * BROWS + t] = g;
            g += cnt;
        }
    }
    __syncthreads();
    // pass B: stable scatter cols into csr
    for (int bt2 = 0; bt2 < nbat; ++bt2) {
        unsigned i = wbeg + (unsigned)(bt2 * 64 + lane);
        bool act = (i < wend);
        unsigned p = act ? (lds_ok ? data[i] : buf[start + i]) : 0u;
        unsigned v = act ? (p >> RLSHIFT) : 1023u;
        unsigned long long m = match_key<10>(v);
        unsigned before = (unsigned)__popcll(m & lmask);
        unsigned total  = (unsigned)__popcll(m);
        int leader = __ffsll(m) - 1;
        unsigned base0 = 0;
        if (act && before == 0u) { base0 = h2[w * BROWS + v]; h2[w * BROWS + v] = base0 + total; }
        base0 = __shfl(base0, leader, 64);
        if (act) csr[base0 + before] = p & COLMASK;
    }
}

// ---- prop: block per (bucket, half); binary-search row, LDS accumulate ----
__global__ void __launch_bounds__(BT)
k_prop(const unsigned* __restrict__ csr, const unsigned* __restrict__ rs,
       const unsigned* __restrict__ hist, const unsigned* __restrict__ bsums,
       const unsigned* __restrict__ lin, unsigned* __restrict__ lout,
       int N, int E, int nbuckets) {
    __shared__ unsigned acc[BROWS];
    __shared__ unsigned offs[BROWS + 1];
    __shared__ unsigned pwt[BROWS];
    int bb = blockIdx.x / SPLIT, pp = blockIdx.x % SPLIT;
    int t = threadIdx.x;
    size_t i0 = (size_t)bb * NCH;
    unsigned start = hist[i0] + bsums[i0 >> 10];
    unsigned end;
    if (bb + 1 < nbuckets) { size_t i1 = (size_t)(bb + 1) * NCH; end = hist[i1] + bsums[i1 >> 10]; }
    else end = (unsigned)E;
    unsigned len = end - start;
    acc[t] = 0u;
    pwt[t] = dpow31((unsigned)t);
    int row = bb * BROWS + t;
    offs[t] = (row < N) ? (rs[row] - start) : len;
    if (t == 0) offs[BROWS] = len;
    __syncthreads();
    unsigned seglen = (len + SPLIT - 1u) / SPLIT;
    unsigned pbeg = pp * seglen;
    unsigned pend = min(pbeg + seglen, len);
    for (unsigned i = pbeg + t; i < pend; i += BT) {
        unsigned col = csr[start + i];
        int lo = 0;
        #pragma unroll
        for (int st = 256; st; st >>= 1) {
            int mid = lo + st;
            if (offs[mid] <= i) lo = mid;
        }
        unsigned ex = offs[lo + 1] - 1u - i;
        unsigned val = lin[col] * ((ex < BROWS) ? pwt[ex] : dpow31(ex));
        atomicAdd(&acc[lo], val);
    }
    __syncthreads();
    if (row < N) atomicAdd(&lout[row], acc[t]);
}

__global__ void __launch_bounds__(BT)
k_out(const unsigned* __restrict__ l0, const unsigned* __restrict__ l1,
      const unsigned* __restrict__ l2, const unsigned* __restrict__ l3,
      int* __restrict__ out, int N) {
    for (int i = blockIdx.x * BT + threadIdx.x; i < N; i += 256 * BT) {
        int a0 = (int)l0[i], a1 = (int)l1[i], a2 = (int)l2[i], a3 = (int)l3[i];
        out[i]         = a3;
        out[N + i]     = a0;
        out[2 * N + i] = a1;
        out[3 * N + i] = a2;
        out[4 * N + i] = a3;
    }
}

extern "C" void kernel_launch(void* const* d_in, const int* in_sizes, int n_in,
                              void* d_out, int out_size, void* d_ws, size_t ws_size,
                              hipStream_t stream) {
    const float* x  = (const float*)d_in[0];
    const int*   ei = (const int*)d_in[1];
    int* out = (int*)d_out;

    int N = in_sizes[0] / WL_D;
    int E = in_sizes[1] / 2;
    int chunk    = (E + NCH - 1) / NCH;        // 6250
    int nbuckets = (N + BROWS - 1) / BROWS;    // 196
    int L        = nbuckets * NCH;             // 100,352
    int ntiles   = (L + 1023) / 1024;          // 98

    // workspace layout (uint32 units) — everything written before read
    unsigned* ws   = (unsigned*)d_ws;
    unsigned* lab0 = ws;               // N
    unsigned* lab1 = lab0 + N;         // N  (zeroed in k_hist_argmax)
    unsigned* lab2 = lab1 + N;         // N  (zeroed)
    unsigned* lab3 = lab2 + N;         // N  (zeroed)
    unsigned* rs   = lab3 + N;         // N
    unsigned* bs   = rs + N;           // 1024
    unsigned* hist = bs + 1024;        // L
    unsigned* buf  = hist + L;         // E
    unsigned* csr  = buf + E;          // E

    k_hist_argmax<<<GRID_F, BT, 0, stream>>>(x, ei, lab0, hist, lab1, N, E, chunk, nbuckets);
    k_scan_tile<<<ntiles, BT, 0, stream>>>(hist, bs, L);
    k_scan_sums<<<1, BT, 0, stream>>>(bs, ntiles);
    k_scatter<<<NCH, BT, 0, stream>>>(ei, hist, bs, buf, E, chunk, nbuckets);
    k_bucket<<<nbuckets, BT, 0, stream>>>(buf, hist, bs, csr, rs, N, E, nbuckets);
    k_prop<<<nbuckets * SPLIT, BT, 0, stream>>>(csr, rs, hist, bs, lab0, lab1, N, E, nbuckets);
    k_prop<<<nbuckets * SPLIT, BT, 0, stream>>>(csr, rs, hist, bs, lab1, lab2, N, E, nbuckets);
    k_prop<<<nbuckets * SPLIT, BT, 0, stream>>>(csr, rs, hist, bs, lab2, lab3, N, E, nbuckets);
    k_out<<<256, BT, 0, stream>>>(lab0, lab1, lab2, lab3, out, N);
}